// Round 9
// baseline (409.544 us; speedup 1.0000x reference)
//
#include <hip/hip_runtime.h>
#include <hip/hip_bf16.h>
#include <math.h>

typedef __attribute__((ext_vector_type(8))) short short8;
typedef __attribute__((ext_vector_type(16))) float f32x16;

#define NB 4096
#define DIM 128
// sqrt(20 * log2(e)) folded into BOTH operands: acc = 28.8539*dot (log2 units)
#define SQS 5.3715828f
#define LN2 0.6931471805599453f

__device__ inline unsigned short f2bf(float f) {
  unsigned int u = __builtin_bit_cast(unsigned int, f);
  u += 0x7FFFu + ((u >> 16) & 1u);
  return (unsigned short)(u >> 16);
}

__device__ inline float wave_sum(float v) {
#pragma unroll
  for (int off = 32; off >= 1; off >>= 1) v += __shfl_xor(v, off, 64);
  return v;
}

// Parallel int64-vs-int32 links detect (all odd words zero <=> int64) + out=0.
__global__ __launch_bounds__(64) void k_init(const int* links32, int* flag, float* out) {
  int t = threadIdx.x;
  bool ok = (links32[1 + 2 * t] == 0) && (links32[129 + 2 * t] == 0);
  unsigned long long m = __ballot(ok);
  if (t == 0) { *flag = (m == ~0ull) ? 1 : 0; out[0] = 0.0f; }
}

// Gather + L2-normalize the 8192 referenced rows; pack bf16 K-chunked layout
// Zc[16][4096][8], PRE-SCALED by SQS (so MFMA acc is in log2-exp units).
__global__ __launch_bounds__(256) void k_normalize(
    const float* __restrict__ emb, const int* __restrict__ links,
    const int* __restrict__ flag,
    unsigned short* __restrict__ Zic, unsigned short* __restrict__ Zjc) {
  int wid = threadIdx.x >> 6, lane = threadIdx.x & 63;
  int r = blockIdx.x * 4 + wid;   // 0..8191
  int side = r >> 12;             // 0 => zis (links[:,0]), 1 => zjs (links[:,1])
  int p = r & (NB - 1);
  int q = 2 * p + side;
  int idx = (*flag) ? links[2 * q] : links[q];  // int64 mode: lo word
  const float* src = emb + (long long)idx * DIM;
  float x0 = src[lane], x1 = src[lane + 64];
  float ss = wave_sum(x0 * x0 + x1 * x1);
  float inv = SQS / fmaxf(sqrtf(ss), 1e-12f);
  unsigned short* Zc = side ? Zjc : Zic;
  Zc[(((lane >> 3) + 0) * NB + p) * 8 + (lane & 7)] = f2bf(x0 * inv);
  Zc[(((lane >> 3) + 8) * NB + p) * 8 + (lane & 7)] = f2bf(x1 * inv);
}

// diagn[p] = ln2 * sum_k Zic[p][k]*Zjc[p][k] = 20*(zi.zj)  (natural-log units)
__global__ __launch_bounds__(256) void k_diag(
    const unsigned short* __restrict__ Zic, const unsigned short* __restrict__ Zjc,
    float* __restrict__ diagn) {
  int wid = threadIdx.x >> 6, lane = threadIdx.x & 63;
  int p = blockIdx.x * 4 + wid;
  size_t off = ((size_t)(lane >> 2) * NB + p) * 8 + (lane & 3) * 2;
  unsigned ui = *reinterpret_cast<const unsigned*>(Zic + off);
  unsigned uj = *reinterpret_cast<const unsigned*>(Zjc + off);
  float i0 = __builtin_bit_cast(float, (ui & 0xFFFFu) << 16);
  float i1 = __builtin_bit_cast(float, ui & 0xFFFF0000u);
  float j0 = __builtin_bit_cast(float, (uj & 0xFFFFu) << 16);
  float j1 = __builtin_bit_cast(float, uj & 0xFFFF0000u);
  float s = wave_sum(i0 * j0 + i1 * j1);
  if (lane == 0) diagn[p] = s * LN2;
}

// Symmetry-halved pass set:
//  z=0 AB (full): rows(i)->a  AND cols(j)->b   (BA == AB^T, pass eliminated)
//  z=1 AA (upper triangle only): rows->a, cols->a; diagonal tiles rows-only+mask
//  z=2 BB (upper): rows->b, cols->b
// Layout-agnostic dual per-reg probe (verified R3-R8) gives imap/jmap/dmask.
// Row partials in regs -> LDS -> rowp[z][by][i]; col partials per tile via
// ds_add_f32 -> colp[z][bx][j]. No global atomics.
__global__ __launch_bounds__(256) void k_pass(
    const unsigned short* __restrict__ Zic, const unsigned short* __restrict__ Zjc,
    float* __restrict__ rowp, float* __restrict__ colp) {
  int z = blockIdx.z;
  const unsigned short* Xc = (z == 2) ? Zjc : Zic;  // rows side
  const unsigned short* Yc = (z == 1) ? Zic : Zjc;  // cols side

  __shared__ float bufr[128];
  __shared__ float bufc[256];
  int tid = threadIdx.x, wid = tid >> 6, lane = tid & 63;
  if (tid < 128) bufr[tid] = 0.0f;
  bufc[tid] = 0.0f;
  __syncthreads();

  int it0 = blockIdx.x * 128 + wid * 32;  // wave's 32 loss-rows
  int jb = blockIdx.y * 256;              // 8 j-tiles of 32
  int lr = lane & 31;
  int hi = lane >> 5;

  // --- dual per-reg layout probe ---
  short8 pj, pc;
  unsigned short blr = f2bf((float)lr);
#pragma unroll
  for (int e = 0; e < 8; ++e) { pj[e] = (short)blr; pc[e] = (short)0x3D80; }
  f32x16 pr = {}, pn = {};
  pr = __builtin_amdgcn_mfma_f32_32x32x16_bf16(pj, pc, pr, 0, 0, 0);
  pn = __builtin_amdgcn_mfma_f32_32x32x16_bf16(pc, pj, pn, 0, 0, 0);
  unsigned int dmask = 0;
  int imv[4] = {0, 0, 0, 0}, jmv[4] = {0, 0, 0, 0};
#pragma unroll
  for (int r = 0; r < 16; ++r) {
    int jm = (int)(pr[r] + 0.5f), im = (int)(pn[r] + 0.5f);
    dmask |= (unsigned)(jm == im) << r;
    imv[r >> 2] |= im << ((r & 3) * 8);
    jmv[r >> 2] |= jm << ((r & 3) * 8);
  }

  short8 xf[8];
#pragma unroll
  for (int ks = 0; ks < 8; ++ks)
    xf[ks] = *reinterpret_cast<const short8*>(
        Xc + ((size_t)(ks * 2 + hi) * NB + (it0 + lr)) * 8);

  float rs[16];
#pragma unroll
  for (int r = 0; r < 16; ++r) rs[r] = 0.0f;

  for (int jt = 0; jt < 8; ++jt) {
    int j0 = jb + jt * 32;
    if (z && j0 < it0) continue;  // lower triangle: covered by transpose
    short8 yf[8];
#pragma unroll
    for (int ks = 0; ks < 8; ++ks)
      yf[ks] = *reinterpret_cast<const short8*>(
          Yc + ((size_t)(ks * 2 + hi) * NB + (j0 + lr)) * 8);
    f32x16 acc = {};
#pragma unroll
    for (int ks = 0; ks < 8; ++ks)
      acc = __builtin_amdgcn_mfma_f32_32x32x16_bf16(yf[ks], xf[ks], acc, 0, 0, 0);
    bool dtile = z && (j0 == it0);          // masked self-tile, rows only
    bool cflush = (z == 0) || (j0 > it0);   // col contribution valid
#pragma unroll
    for (int r = 0; r < 16; ++r) {
      float e = exp2f(acc[r]);
      if (dtile && ((dmask >> r) & 1u)) e = 0.0f;
      rs[r] += e;
      if (cflush) {
        int jm = (jmv[r >> 2] >> ((r & 3) * 8)) & 0xFF;
        atomicAdd(&bufc[jt * 32 + jm], e);
      }
    }
  }
  // row reduce through LDS (2 lanes share each row)
#pragma unroll
  for (int r = 0; r < 16; ++r) {
    int im = (imv[r >> 2] >> ((r & 3) * 8)) & 0xFF;
    atomicAdd(&bufr[wid * 32 + im], rs[r]);
  }
  __syncthreads();
  if (tid < 128)
    rowp[((size_t)z * 16 + blockIdx.y) * NB + blockIdx.x * 128 + tid] = bufr[tid];
  colp[((size_t)z * 32 + blockIdx.x) * NB + jb + tid] = bufc[tid];
}

// sa[i] = rows_AB + rows_AA + cols_AA ; sb[i] = rows_BB + cols_AB + cols_BB
// loss = mean(0.5*(ln sa + ln sb) - diagn)
__global__ __launch_bounds__(256) void k_final(
    const float* __restrict__ rowp, const float* __restrict__ colp,
    const float* __restrict__ diagn, float* __restrict__ out) {
  int i = blockIdx.x * 256 + threadIdx.x;
  float sa = 0.0f, sb = 0.0f;
#pragma unroll
  for (int y = 0; y < 16; ++y) {
    sa += rowp[(size_t)(0 * 16 + y) * NB + i] + rowp[(size_t)(1 * 16 + y) * NB + i];
    sb += rowp[(size_t)(2 * 16 + y) * NB + i];
  }
#pragma unroll
  for (int x = 0; x < 32; ++x) {
    sa += colp[(size_t)(1 * 32 + x) * NB + i];
    sb += colp[(size_t)(0 * 32 + x) * NB + i] + colp[(size_t)(2 * 32 + x) * NB + i];
  }
  float v = 0.5f * (logf(sa) + logf(sb)) - diagn[i];
  v = wave_sum(v);
  __shared__ float sred[4];
  if ((threadIdx.x & 63) == 0) sred[threadIdx.x >> 6] = v;
  __syncthreads();
  if (threadIdx.x == 0)
    atomicAdd(out, (sred[0] + sred[1] + sred[2] + sred[3]) * (1.0f / NB));
}

extern "C" void kernel_launch(void* const* d_in, const int* in_sizes, int n_in,
                              void* d_out, int out_size, void* d_ws, size_t ws_size,
                              hipStream_t stream) {
  const float* emb = (const float*)d_in[0];
  const int* links = (const int*)d_in[1];
  char* ws = (char*)d_ws;
  unsigned short* Zic = (unsigned short*)(ws + 0);       // 1 MB
  unsigned short* Zjc = (unsigned short*)(ws + 1048576); // 1 MB
  float* rowp = (float*)(ws + 2097152);                  // 3*16*4096*4 = 768 KB
  float* colp = (float*)(ws + 2883584);                  // 3*32*4096*4 = 1.5 MB
  float* diagn = (float*)(ws + 4456448);                 // 16 KB
  int* flag = (int*)(ws + 4472832);                      // 4 B
  float* out = (float*)d_out;

  hipLaunchKernelGGL(k_init, dim3(1), dim3(64), 0, stream, links, flag, out);
  hipLaunchKernelGGL(k_normalize, dim3(2048), dim3(256), 0, stream,
                     emb, links, flag, Zic, Zjc);
  hipLaunchKernelGGL(k_diag, dim3(1024), dim3(256), 0, stream, Zic, Zjc, diagn);
  hipLaunchKernelGGL(k_pass, dim3(32, 16, 3), dim3(256), 0, stream,
                     Zic, Zjc, rowp, colp);
  hipLaunchKernelGGL(k_final, dim3(16), dim3(256), 0, stream,
                     rowp, colp, diagn, out);
}

// Round 10
// 70.313 us; speedup vs baseline: 5.8246x; 5.8246x over previous
//
#include <hip/hip_runtime.h>
#include <hip/hip_bf16.h>
#include <math.h>

typedef __attribute__((ext_vector_type(8))) short short8;
typedef __attribute__((ext_vector_type(16))) float f32x16;

#define NB 4096
#define DIM 128
// sqrt(20 * log2(e)) folded into BOTH operands: acc = 28.8539*dot (log2 units)
#define SQS 5.3715828f
#define LN2 0.6931471805599453f

__device__ inline unsigned short f2bf(float f) {
  unsigned int u = __builtin_bit_cast(unsigned int, f);
  u += 0x7FFFu + ((u >> 16) & 1u);
  return (unsigned short)(u >> 16);
}

__device__ inline float wave_sum(float v) {
#pragma unroll
  for (int off = 32; off >= 1; off >>= 1) v += __shfl_xor(v, off, 64);
  return v;
}

// Parallel int64-vs-int32 links detect (all odd words zero <=> int64) + out=0.
__global__ __launch_bounds__(64) void k_init(const int* links32, int* flag, float* out) {
  int t = threadIdx.x;
  bool ok = (links32[1 + 2 * t] == 0) && (links32[129 + 2 * t] == 0);
  unsigned long long m = __ballot(ok);
  if (t == 0) { *flag = (m == ~0ull) ? 1 : 0; out[0] = 0.0f; }
}

// Gather + L2-normalize the 8192 referenced rows; pack bf16 K-chunked layout
// Zc[16][4096][8], PRE-SCALED by SQS (so MFMA acc is in log2-exp units).
__global__ __launch_bounds__(256) void k_normalize(
    const float* __restrict__ emb, const int* __restrict__ links,
    const int* __restrict__ flag,
    unsigned short* __restrict__ Zic, unsigned short* __restrict__ Zjc) {
  int wid = threadIdx.x >> 6, lane = threadIdx.x & 63;
  int r = blockIdx.x * 4 + wid;   // 0..8191
  int side = r >> 12;             // 0 => zis (links[:,0]), 1 => zjs (links[:,1])
  int p = r & (NB - 1);
  int q = 2 * p + side;
  int idx = (*flag) ? links[2 * q] : links[q];  // int64 mode: lo word
  const float* src = emb + (long long)idx * DIM;
  float x0 = src[lane], x1 = src[lane + 64];
  float ss = wave_sum(x0 * x0 + x1 * x1);
  float inv = SQS / fmaxf(sqrtf(ss), 1e-12f);
  unsigned short* Zc = side ? Zjc : Zic;
  Zc[(((lane >> 3) + 0) * NB + p) * 8 + (lane & 7)] = f2bf(x0 * inv);
  Zc[(((lane >> 3) + 8) * NB + p) * 8 + (lane & 7)] = f2bf(x1 * inv);
}

// diagn[p] = ln2 * sum_k Zic[p][k]*Zjc[p][k] = 20*(zi.zj)  (natural-log units)
__global__ __launch_bounds__(256) void k_diag(
    const unsigned short* __restrict__ Zic, const unsigned short* __restrict__ Zjc,
    float* __restrict__ diagn) {
  int wid = threadIdx.x >> 6, lane = threadIdx.x & 63;
  int p = blockIdx.x * 4 + wid;
  size_t off = ((size_t)(lane >> 2) * NB + p) * 8 + (lane & 3) * 2;
  unsigned ui = *reinterpret_cast<const unsigned*>(Zic + off);
  unsigned uj = *reinterpret_cast<const unsigned*>(Zjc + off);
  float i0 = __builtin_bit_cast(float, (ui & 0xFFFFu) << 16);
  float i1 = __builtin_bit_cast(float, ui & 0xFFFF0000u);
  float j0 = __builtin_bit_cast(float, (uj & 0xFFFFu) << 16);
  float j1 = __builtin_bit_cast(float, uj & 0xFFFF0000u);
  float s = wave_sum(i0 * j0 + i1 * j1);
  if (lane == 0) diagn[p] = s * LN2;
}

// FUSED pass: all four Gram products in one j-loop, sharing operand loads.
// Wave owns rows it0..it0+31 of BOTH Zi (xi) and Zj (xj). Per j-tile:
//   yj (Zj cols) -> AB = yj.xi^T (rows->a), BB = yj.xj^T (rows->b, diag-skip)
//   yi (Zi cols) -> AA = yi.xi^T (rows->a, diag-skip), BA = yi.xj^T (rows->b)
// yi loads issue between the chain pairs so their latency hides under the
// AB/BB epilogue (32 exp2 + adds); chains are pairwise independent (2-way ILP).
// Row sums only, in registers; one LDS reduce at the end. Layout-agnostic via
// the dual per-reg probe (verified R3-R9).
__global__ __launch_bounds__(256, 2) void k_pass(
    const unsigned short* __restrict__ Zic, const unsigned short* __restrict__ Zjc,
    float* __restrict__ rowp_a, float* __restrict__ rowp_b) {
  __shared__ float bufa[128], bufb[128];
  int tid = threadIdx.x, wid = tid >> 6, lane = tid & 63;
  if (tid < 128) { bufa[tid] = 0.0f; bufb[tid] = 0.0f; }
  __syncthreads();

  int it0 = blockIdx.x * 128 + wid * 32;  // wave's 32 loss-rows
  int jb = blockIdx.y * 256;              // 8 j-tiles of 32
  int lr = lane & 31;
  int hi = lane >> 5;

  // --- dual per-reg layout probe ---
  short8 pj, pc;
  unsigned short blr = f2bf((float)lr);
#pragma unroll
  for (int e = 0; e < 8; ++e) { pj[e] = (short)blr; pc[e] = (short)0x3D80; }
  f32x16 pr = {}, pn = {};
  pr = __builtin_amdgcn_mfma_f32_32x32x16_bf16(pj, pc, pr, 0, 0, 0);
  pn = __builtin_amdgcn_mfma_f32_32x32x16_bf16(pc, pj, pn, 0, 0, 0);
  unsigned int dmask = 0;
  int imv[4] = {0, 0, 0, 0};
#pragma unroll
  for (int r = 0; r < 16; ++r) {
    int jm = (int)(pr[r] + 0.5f), im = (int)(pn[r] + 0.5f);
    dmask |= (unsigned)(jm == im) << r;
    imv[r >> 2] |= im << ((r & 3) * 8);
  }

  // X fragments for the whole j-loop: 32 rows of Zi and of Zj
  short8 xi[8], xj[8];
#pragma unroll
  for (int ks = 0; ks < 8; ++ks) {
    size_t o = ((size_t)(ks * 2 + hi) * NB + (it0 + lr)) * 8;
    xi[ks] = *reinterpret_cast<const short8*>(Zic + o);
    xj[ks] = *reinterpret_cast<const short8*>(Zjc + o);
  }

  float ra[16], rb[16];
#pragma unroll
  for (int r = 0; r < 16; ++r) { ra[r] = 0.0f; rb[r] = 0.0f; }

  for (int jt = 0; jt < 8; ++jt) {
    int j0 = jb + jt * 32;
    bool dt = (j0 == it0);
    short8 yj[8];
#pragma unroll
    for (int ks = 0; ks < 8; ++ks)
      yj[ks] = *reinterpret_cast<const short8*>(
          Zjc + ((size_t)(ks * 2 + hi) * NB + (j0 + lr)) * 8);
    f32x16 pab = {}, pbb = {};
#pragma unroll
    for (int ks = 0; ks < 8; ++ks)
      pab = __builtin_amdgcn_mfma_f32_32x32x16_bf16(yj[ks], xi[ks], pab, 0, 0, 0);
#pragma unroll
    for (int ks = 0; ks < 8; ++ks)
      pbb = __builtin_amdgcn_mfma_f32_32x32x16_bf16(yj[ks], xj[ks], pbb, 0, 0, 0);
    short8 yi[8];  // issue now: latency hides under the AB/BB epilogue
#pragma unroll
    for (int ks = 0; ks < 8; ++ks)
      yi[ks] = *reinterpret_cast<const short8*>(
          Zic + ((size_t)(ks * 2 + hi) * NB + (j0 + lr)) * 8);
#pragma unroll
    for (int r = 0; r < 16; ++r) {
      float ea = exp2f(pab[r]);
      float eb = exp2f(pbb[r]);
      if (dt && ((dmask >> r) & 1u)) eb = 0.0f;  // BB diag skip
      ra[r] += ea;
      rb[r] += eb;
    }
    f32x16 paa = {}, pba = {};
#pragma unroll
    for (int ks = 0; ks < 8; ++ks)
      paa = __builtin_amdgcn_mfma_f32_32x32x16_bf16(yi[ks], xi[ks], paa, 0, 0, 0);
#pragma unroll
    for (int ks = 0; ks < 8; ++ks)
      pba = __builtin_amdgcn_mfma_f32_32x32x16_bf16(yi[ks], xj[ks], pba, 0, 0, 0);
#pragma unroll
    for (int r = 0; r < 16; ++r) {
      float ea = exp2f(paa[r]);
      if (dt && ((dmask >> r) & 1u)) ea = 0.0f;  // AA diag skip
      float eb = exp2f(pba[r]);
      ra[r] += ea;
      rb[r] += eb;
    }
  }
  // LDS reduce (2 lanes x 16 regs share each output row)
#pragma unroll
  for (int r = 0; r < 16; ++r) {
    int im = (imv[r >> 2] >> ((r & 3) * 8)) & 0xFF;
    atomicAdd(&bufa[wid * 32 + im], ra[r]);
    atomicAdd(&bufb[wid * 32 + im], rb[r]);
  }
  __syncthreads();
  if (tid < 128) {
    rowp_a[(size_t)blockIdx.y * NB + blockIdx.x * 128 + tid] = bufa[tid];
    rowp_b[(size_t)blockIdx.y * NB + blockIdx.x * 128 + tid] = bufb[tid];
  }
}

// loss = mean(0.5*(ln sa + ln sb) - diagn)   (e^{+20} scale cancels in ln)
__global__ __launch_bounds__(256) void k_final(
    const float* __restrict__ rowp_a, const float* __restrict__ rowp_b,
    const float* __restrict__ diagn, float* __restrict__ out) {
  int i = blockIdx.x * 256 + threadIdx.x;
  float sa = 0.0f, sb = 0.0f;
#pragma unroll
  for (int y = 0; y < 16; ++y) {
    sa += rowp_a[(size_t)y * NB + i];
    sb += rowp_b[(size_t)y * NB + i];
  }
  float v = 0.5f * (logf(sa) + logf(sb)) - diagn[i];
  v = wave_sum(v);
  __shared__ float sred[4];
  if ((threadIdx.x & 63) == 0) sred[threadIdx.x >> 6] = v;
  __syncthreads();
  if (threadIdx.x == 0)
    atomicAdd(out, (sred[0] + sred[1] + sred[2] + sred[3]) * (1.0f / NB));
}

extern "C" void kernel_launch(void* const* d_in, const int* in_sizes, int n_in,
                              void* d_out, int out_size, void* d_ws, size_t ws_size,
                              hipStream_t stream) {
  const float* emb = (const float*)d_in[0];
  const int* links = (const int*)d_in[1];
  char* ws = (char*)d_ws;
  unsigned short* Zic = (unsigned short*)(ws + 0);       // 1 MB
  unsigned short* Zjc = (unsigned short*)(ws + 1048576); // 1 MB
  float* rowp_a = (float*)(ws + 2097152);                // 16*4096*4 = 256 KB
  float* rowp_b = (float*)(ws + 2359296);                // 256 KB
  float* diagn = (float*)(ws + 2621440);                 // 16 KB
  int* flag = (int*)(ws + 2637824);                      // 4 B
  float* out = (float*)d_out;

  hipLaunchKernelGGL(k_init, dim3(1), dim3(64), 0, stream, links, flag, out);
  hipLaunchKernelGGL(k_normalize, dim3(2048), dim3(256), 0, stream,
                     emb, links, flag, Zic, Zjc);
  hipLaunchKernelGGL(k_diag, dim3(1024), dim3(256), 0, stream, Zic, Zjc, diagn);
  hipLaunchKernelGGL(k_pass, dim3(32, 16), dim3(256), 0, stream,
                     Zic, Zjc, rowp_a, rowp_b);
  hipLaunchKernelGGL(k_final, dim3(16), dim3(256), 0, stream,
                     rowp_a, rowp_b, diagn, out);
}

// Round 11
// 60.946 us; speedup vs baseline: 6.7197x; 1.1537x over previous
//
#include <hip/hip_runtime.h>
#include <hip/hip_bf16.h>
#include <math.h>

typedef __attribute__((ext_vector_type(8))) short short8;
typedef __attribute__((ext_vector_type(16))) float f32x16;

#define NB 4096
#define DIM 128
// sqrt(20 * log2(e)) folded into BOTH operands: acc = 28.8539*dot (log2 units)
#define SQS 5.3715828f

__device__ inline unsigned short f2bf(float f) {
  unsigned int u = __builtin_bit_cast(unsigned int, f);
  u += 0x7FFFu + ((u >> 16) & 1u);
  return (unsigned short)(u >> 16);
}

__device__ inline float wave_sum(float v) {
#pragma unroll
  for (int off = 32; off >= 1; off >>= 1) v += __shfl_xor(v, off, 64);
  return v;
}

// Parallel int64-vs-int32 links detect (all odd words zero <=> int64) + out=0.
__global__ __launch_bounds__(64) void k_init(const int* links32, int* flag, float* out) {
  int t = threadIdx.x;
  bool ok = (links32[1 + 2 * t] == 0) && (links32[129 + 2 * t] == 0);
  unsigned long long m = __ballot(ok);
  if (t == 0) { *flag = (m == ~0ull) ? 1 : 0; out[0] = 0.0f; }
}

// Pair-per-wave gather + L2-normalize + f32 diag (k_diag merged in).
// Packs bf16 K-chunked layout Zc[16][4096][8], PRE-SCALED by SQS.
// diagn[p] = 20 * (zi_p . zj_p)  (natural-log units)
__global__ __launch_bounds__(256) void k_normalize(
    const float* __restrict__ emb, const int* __restrict__ links,
    const int* __restrict__ flag,
    unsigned short* __restrict__ Zic, unsigned short* __restrict__ Zjc,
    float* __restrict__ diagn) {
  int wid = threadIdx.x >> 6, lane = threadIdx.x & 63;
  int p = blockIdx.x * 4 + wid;   // pair index 0..4095
  int fl = *flag;
  int idx_i = fl ? links[4 * p + 0] : links[2 * p + 0];
  int idx_j = fl ? links[4 * p + 2] : links[2 * p + 1];
  const float* si = emb + (long long)idx_i * DIM;
  const float* sj = emb + (long long)idx_j * DIM;
  float a0 = si[lane], a1 = si[lane + 64];
  float b0 = sj[lane], b1 = sj[lane + 64];
  float sii = wave_sum(a0 * a0 + a1 * a1);
  float sjj = wave_sum(b0 * b0 + b1 * b1);
  float sij = wave_sum(a0 * b0 + a1 * b1);
  float ni = fmaxf(sqrtf(sii), 1e-12f);
  float nj = fmaxf(sqrtf(sjj), 1e-12f);
  if (lane == 0) diagn[p] = 20.0f * sij / (ni * nj);
  float wi = SQS / ni, wj = SQS / nj;
  size_t o0 = (((size_t)(lane >> 3) + 0) * NB + p) * 8 + (lane & 7);
  size_t o1 = (((size_t)(lane >> 3) + 8) * NB + p) * 8 + (lane & 7);
  Zic[o0] = f2bf(a0 * wi);
  Zic[o1] = f2bf(a1 * wi);
  Zjc[o0] = f2bf(b0 * wj);
  Zjc[o1] = f2bf(b1 * wj);
}

// FUSED pass, LDS-shared Y tiles (2-phase double-buffer, issue-early/write-late).
// Per j-tile the block stages yj(Zjc)+yi(Zic) [16 KB] ONCE; all 4 waves read
// from LDS (per-thread VMEM 16 -> 4 loads/tile). Per ks: 2 ds_read_b128 feed
// 4 independent MFMA chains (AB,BB,AA,BA). Row sums in regs; epilogue exps
// overlap the async staging; one barrier per tile.
// Layout-agnostic dual per-reg probe (verified R3-R10).
__global__ __launch_bounds__(256, 2) void k_pass(
    const unsigned short* __restrict__ Zic, const unsigned short* __restrict__ Zjc,
    float* __restrict__ rowp_a, float* __restrict__ rowp_b) {
  __shared__ unsigned short yt[2][2][4096];  // [dbuf][side 0=yj,1=yi][piece*8] 32 KB
  __shared__ float bufa[128], bufb[128];
  int tid = threadIdx.x, wid = tid >> 6, lane = tid & 63;
  if (tid < 128) { bufa[tid] = 0.0f; bufb[tid] = 0.0f; }

  int it0 = blockIdx.x * 128 + wid * 32;  // wave's 32 loss-rows
  int jb = blockIdx.y * 256;              // 8 j-tiles of 32
  int lr = lane & 31;
  int hi = lane >> 5;

  // --- dual per-reg layout probe ---
  short8 pj, pc;
  unsigned short blr = f2bf((float)lr);
#pragma unroll
  for (int e = 0; e < 8; ++e) { pj[e] = (short)blr; pc[e] = (short)0x3D80; }
  f32x16 pr = {}, pn = {};
  pr = __builtin_amdgcn_mfma_f32_32x32x16_bf16(pj, pc, pr, 0, 0, 0);
  pn = __builtin_amdgcn_mfma_f32_32x32x16_bf16(pc, pj, pn, 0, 0, 0);
  unsigned int dmask = 0;
  int imv[4] = {0, 0, 0, 0};
#pragma unroll
  for (int r = 0; r < 16; ++r) {
    int jm = (int)(pr[r] + 0.5f), im = (int)(pn[r] + 0.5f);
    dmask |= (unsigned)(jm == im) << r;
    imv[r >> 2] |= im << ((r & 3) * 8);
  }

  // X fragments for the whole j-loop: 32 rows of Zi and of Zj
  short8 xi[8], xj[8];
#pragma unroll
  for (int ks = 0; ks < 8; ++ks) {
    size_t o = ((size_t)(ks * 2 + hi) * NB + (it0 + lr)) * 8;
    xi[ks] = *reinterpret_cast<const short8*>(Zic + o);
    xj[ks] = *reinterpret_cast<const short8*>(Zjc + o);
  }

  float ra[16], rb[16];
#pragma unroll
  for (int r = 0; r < 16; ++r) { ra[r] = 0.0f; rb[r] = 0.0f; }

  // staging geometry: piece q*256+tid -> chunk p>>5, row p&31, lds ofs p*8
  // prologue: stage tile 0 into buffer 0
#pragma unroll
  for (int q = 0; q < 2; ++q) {
    int p = q * 256 + tid;
    size_t go = ((size_t)(p >> 5) * NB + (jb + (p & 31))) * 8;
    *reinterpret_cast<short8*>(&yt[0][0][p * 8]) =
        *reinterpret_cast<const short8*>(Zjc + go);
    *reinterpret_cast<short8*>(&yt[0][1][p * 8]) =
        *reinterpret_cast<const short8*>(Zic + go);
  }
  __syncthreads();

  for (int jt = 0; jt < 8; ++jt) {
    int cur = jt & 1, nxt = cur ^ 1;
    int j0 = jb + jt * 32;
    bool dt = (j0 == it0);
    short8 tj0, ti0, tj1, ti1;
    if (jt < 7) {  // issue-early: next tile's 4 global loads
      int j0n = j0 + 32;
      size_t g0 = ((size_t)(tid >> 5) * NB + (j0n + (tid & 31))) * 8;
      size_t g1 = ((size_t)((tid + 256) >> 5) * NB + (j0n + (tid & 31))) * 8;
      tj0 = *reinterpret_cast<const short8*>(Zjc + g0);
      ti0 = *reinterpret_cast<const short8*>(Zic + g0);
      tj1 = *reinterpret_cast<const short8*>(Zjc + g1);
      ti1 = *reinterpret_cast<const short8*>(Zic + g1);
    }
    f32x16 pab = {}, pbb = {}, paa = {}, pba = {};
#pragma unroll
    for (int ks = 0; ks < 8; ++ks) {
      int off = ((ks * 2 + hi) * 32 + lr) * 8;
      short8 yj = *reinterpret_cast<const short8*>(&yt[cur][0][off]);
      short8 yi = *reinterpret_cast<const short8*>(&yt[cur][1][off]);
      pab = __builtin_amdgcn_mfma_f32_32x32x16_bf16(yj, xi[ks], pab, 0, 0, 0);
      pbb = __builtin_amdgcn_mfma_f32_32x32x16_bf16(yj, xj[ks], pbb, 0, 0, 0);
      paa = __builtin_amdgcn_mfma_f32_32x32x16_bf16(yi, xi[ks], paa, 0, 0, 0);
      pba = __builtin_amdgcn_mfma_f32_32x32x16_bf16(yi, xj[ks], pba, 0, 0, 0);
    }
    if (jt < 7) {  // write-late: staging lands after the MFMAs
      *reinterpret_cast<short8*>(&yt[nxt][0][tid * 8]) = tj0;
      *reinterpret_cast<short8*>(&yt[nxt][1][tid * 8]) = ti0;
      *reinterpret_cast<short8*>(&yt[nxt][0][(tid + 256) * 8]) = tj1;
      *reinterpret_cast<short8*>(&yt[nxt][1][(tid + 256) * 8]) = ti1;
    }
#pragma unroll
    for (int r = 0; r < 16; ++r) {
      float eab = exp2f(pab[r]);
      float ebb = exp2f(pbb[r]);
      float eaa = exp2f(paa[r]);
      float eba = exp2f(pba[r]);
      if (dt && ((dmask >> r) & 1u)) { ebb = 0.0f; eaa = 0.0f; }  // diag skips
      ra[r] += eab + eaa;
      rb[r] += ebb + eba;
    }
    __syncthreads();  // nxt fully staged; cur free for overwrite next iter
  }
  // LDS reduce (2 lanes x 16 regs share each output row)
#pragma unroll
  for (int r = 0; r < 16; ++r) {
    int im = (imv[r >> 2] >> ((r & 3) * 8)) & 0xFF;
    atomicAdd(&bufa[wid * 32 + im], ra[r]);
    atomicAdd(&bufb[wid * 32 + im], rb[r]);
  }
  __syncthreads();
  if (tid < 128) {
    rowp_a[(size_t)blockIdx.y * NB + blockIdx.x * 128 + tid] = bufa[tid];
    rowp_b[(size_t)blockIdx.y * NB + blockIdx.x * 128 + tid] = bufb[tid];
  }
}

// loss = mean(0.5*(ln sa + ln sb) - diagn)   (e^{+20} scale cancels in ln)
__global__ __launch_bounds__(256) void k_final(
    const float* __restrict__ rowp_a, const float* __restrict__ rowp_b,
    const float* __restrict__ diagn, float* __restrict__ out) {
  int i = blockIdx.x * 256 + threadIdx.x;
  float sa = 0.0f, sb = 0.0f;
#pragma unroll
  for (int y = 0; y < 16; ++y) {
    sa += rowp_a[(size_t)y * NB + i];
    sb += rowp_b[(size_t)y * NB + i];
  }
  float v = 0.5f * (logf(sa) + logf(sb)) - diagn[i];
  v = wave_sum(v);
  __shared__ float sred[4];
  if ((threadIdx.x & 63) == 0) sred[threadIdx.x >> 6] = v;
  __syncthreads();
  if (threadIdx.x == 0)
    atomicAdd(out, (sred[0] + sred[1] + sred[2] + sred[3]) * (1.0f / NB));
}

extern "C" void kernel_launch(void* const* d_in, const int* in_sizes, int n_in,
                              void* d_out, int out_size, void* d_ws, size_t ws_size,
                              hipStream_t stream) {
  const float* emb = (const float*)d_in[0];
  const int* links = (const int*)d_in[1];
  char* ws = (char*)d_ws;
  unsigned short* Zic = (unsigned short*)(ws + 0);       // 1 MB
  unsigned short* Zjc = (unsigned short*)(ws + 1048576); // 1 MB
  float* rowp_a = (float*)(ws + 2097152);                // 16*4096*4 = 256 KB
  float* rowp_b = (float*)(ws + 2359296);                // 256 KB
  float* diagn = (float*)(ws + 2621440);                 // 16 KB
  int* flag = (int*)(ws + 2637824);                      // 4 B
  float* out = (float*)d_out;

  hipLaunchKernelGGL(k_init, dim3(1), dim3(64), 0, stream, links, flag, out);
  hipLaunchKernelGGL(k_normalize, dim3(1024), dim3(256), 0, stream,
                     emb, links, flag, Zic, Zjc, diagn);
  hipLaunchKernelGGL(k_pass, dim3(32, 16), dim3(256), 0, stream,
                     Zic, Zjc, rowp_a, rowp_b);
  hipLaunchKernelGGL(k_final, dim3(16), dim3(256), 0, stream,
                     rowp_a, rowp_b, diagn, out);
}

// Round 12
// 54.291 us; speedup vs baseline: 7.5435x; 1.1226x over previous
//
#include <hip/hip_runtime.h>
#include <hip/hip_bf16.h>
#include <math.h>

typedef __attribute__((ext_vector_type(8))) short short8;
typedef __attribute__((ext_vector_type(16))) float f32x16;

#define NB 4096
#define DIM 128
// sqrt(20 * log2(e)) folded into BOTH operands: acc = 28.8539*dot (log2 units)
#define SQS 5.3715828f

// Raw v_exp_f32 (domain |x|<=28.9 is far from the denormal range OCML's
// exp2f fixup guards, so the 1-instruction form is exact here).
#if __has_builtin(__builtin_amdgcn_exp2f)
#define EX2(x) __builtin_amdgcn_exp2f(x)
#else
#define EX2(x) exp2f(x)
#endif

__device__ inline unsigned short f2bf(float f) {
  unsigned int u = __builtin_bit_cast(unsigned int, f);
  u += 0x7FFFu + ((u >> 16) & 1u);
  return (unsigned short)(u >> 16);
}

__device__ inline float wave_sum(float v) {
#pragma unroll
  for (int off = 32; off >= 1; off >>= 1) v += __shfl_xor(v, off, 64);
  return v;
}

// Parallel int64-vs-int32 links detect (all odd words zero <=> int64) + out=0.
__global__ __launch_bounds__(64) void k_init(const int* links32, int* flag, float* out) {
  int t = threadIdx.x;
  bool ok = (links32[1 + 2 * t] == 0) && (links32[129 + 2 * t] == 0);
  unsigned long long m = __ballot(ok);
  if (t == 0) { *flag = (m == ~0ull) ? 1 : 0; out[0] = 0.0f; }
}

// Pair-per-wave gather + L2-normalize + f32 diag.
// Packs bf16 K-chunked layout Zc[16][4096][8], PRE-SCALED by SQS.
// diagn[p] = 20 * (zi_p . zj_p)  (natural-log units)
__global__ __launch_bounds__(256) void k_normalize(
    const float* __restrict__ emb, const int* __restrict__ links,
    const int* __restrict__ flag,
    unsigned short* __restrict__ Zic, unsigned short* __restrict__ Zjc,
    float* __restrict__ diagn) {
  int wid = threadIdx.x >> 6, lane = threadIdx.x & 63;
  int p = blockIdx.x * 4 + wid;   // pair index 0..4095
  int fl = *flag;
  int idx_i = fl ? links[4 * p + 0] : links[2 * p + 0];
  int idx_j = fl ? links[4 * p + 2] : links[2 * p + 1];
  const float* si = emb + (long long)idx_i * DIM;
  const float* sj = emb + (long long)idx_j * DIM;
  float a0 = si[lane], a1 = si[lane + 64];
  float b0 = sj[lane], b1 = sj[lane + 64];
  float sii = wave_sum(a0 * a0 + a1 * a1);
  float sjj = wave_sum(b0 * b0 + b1 * b1);
  float sij = wave_sum(a0 * b0 + a1 * b1);
  float ni = fmaxf(sqrtf(sii), 1e-12f);
  float nj = fmaxf(sqrtf(sjj), 1e-12f);
  if (lane == 0) diagn[p] = 20.0f * sij / (ni * nj);
  float wi = SQS / ni, wj = SQS / nj;
  size_t o0 = (((size_t)(lane >> 3) + 0) * NB + p) * 8 + (lane & 7);
  size_t o1 = (((size_t)(lane >> 3) + 8) * NB + p) * 8 + (lane & 7);
  Zic[o0] = f2bf(a0 * wi);
  Zic[o1] = f2bf(a1 * wi);
  Zjc[o0] = f2bf(b0 * wj);
  Zjc[o1] = f2bf(b1 * wj);
}

// FUSED pass, LDS-shared Y tiles (2-phase double-buffer, issue-early/write-late).
// Per j-tile the block stages yj(Zjc)+yi(Zic) [16 KB] ONCE; all 4 waves read
// from LDS. Per ks: 2 ds_read_b128 feed 4 independent MFMA chains (AB,BB,AA,BA).
// Row sums in regs; epilogue exps overlap staging; one barrier per tile.
// Layout-agnostic dual per-reg probe (verified R3-R11).
__global__ __launch_bounds__(256, 2) void k_pass(
    const unsigned short* __restrict__ Zic, const unsigned short* __restrict__ Zjc,
    float* __restrict__ rowp_a, float* __restrict__ rowp_b) {
  __shared__ unsigned short yt[2][2][4096];  // [dbuf][side 0=yj,1=yi][piece*8] 32 KB
  __shared__ float bufa[128], bufb[128];
  int tid = threadIdx.x, wid = tid >> 6, lane = tid & 63;
  if (tid < 128) { bufa[tid] = 0.0f; bufb[tid] = 0.0f; }

  int it0 = blockIdx.x * 128 + wid * 32;  // wave's 32 loss-rows
  int jb = blockIdx.y * 256;              // 8 j-tiles of 32
  int lr = lane & 31;
  int hi = lane >> 5;

  // --- dual per-reg layout probe ---
  short8 pj, pc;
  unsigned short blr = f2bf((float)lr);
#pragma unroll
  for (int e = 0; e < 8; ++e) { pj[e] = (short)blr; pc[e] = (short)0x3D80; }
  f32x16 pr = {}, pn = {};
  pr = __builtin_amdgcn_mfma_f32_32x32x16_bf16(pj, pc, pr, 0, 0, 0);
  pn = __builtin_amdgcn_mfma_f32_32x32x16_bf16(pc, pj, pn, 0, 0, 0);
  unsigned int dmask = 0;
  int imv[4] = {0, 0, 0, 0};
#pragma unroll
  for (int r = 0; r < 16; ++r) {
    int jm = (int)(pr[r] + 0.5f), im = (int)(pn[r] + 0.5f);
    dmask |= (unsigned)(jm == im) << r;
    imv[r >> 2] |= im << ((r & 3) * 8);
  }

  // X fragments for the whole j-loop: 32 rows of Zi and of Zj
  short8 xi[8], xj[8];
#pragma unroll
  for (int ks = 0; ks < 8; ++ks) {
    size_t o = ((size_t)(ks * 2 + hi) * NB + (it0 + lr)) * 8;
    xi[ks] = *reinterpret_cast<const short8*>(Zic + o);
    xj[ks] = *reinterpret_cast<const short8*>(Zjc + o);
  }

  float ra[16], rb[16];
#pragma unroll
  for (int r = 0; r < 16; ++r) { ra[r] = 0.0f; rb[r] = 0.0f; }

  // staging geometry: piece q*256+tid -> chunk p>>5, row p&31, lds ofs p*8
  // prologue: stage tile 0 into buffer 0
#pragma unroll
  for (int q = 0; q < 2; ++q) {
    int p = q * 256 + tid;
    size_t go = ((size_t)(p >> 5) * NB + (jb + (p & 31))) * 8;
    *reinterpret_cast<short8*>(&yt[0][0][p * 8]) =
        *reinterpret_cast<const short8*>(Zjc + go);
    *reinterpret_cast<short8*>(&yt[0][1][p * 8]) =
        *reinterpret_cast<const short8*>(Zic + go);
  }
  __syncthreads();

  for (int jt = 0; jt < 8; ++jt) {
    int cur = jt & 1, nxt = cur ^ 1;
    int j0 = jb + jt * 32;
    bool dt = (j0 == it0);
    short8 tj0, ti0, tj1, ti1;
    if (jt < 7) {  // issue-early: next tile's 4 global loads
      int j0n = j0 + 32;
      size_t g0 = ((size_t)(tid >> 5) * NB + (j0n + (tid & 31))) * 8;
      size_t g1 = ((size_t)((tid + 256) >> 5) * NB + (j0n + (tid & 31))) * 8;
      tj0 = *reinterpret_cast<const short8*>(Zjc + g0);
      ti0 = *reinterpret_cast<const short8*>(Zic + g0);
      tj1 = *reinterpret_cast<const short8*>(Zjc + g1);
      ti1 = *reinterpret_cast<const short8*>(Zic + g1);
    }
    f32x16 pab = {}, pbb = {}, paa = {}, pba = {};
#pragma unroll
    for (int ks = 0; ks < 8; ++ks) {
      int off = ((ks * 2 + hi) * 32 + lr) * 8;
      short8 yj = *reinterpret_cast<const short8*>(&yt[cur][0][off]);
      short8 yi = *reinterpret_cast<const short8*>(&yt[cur][1][off]);
      pab = __builtin_amdgcn_mfma_f32_32x32x16_bf16(yj, xi[ks], pab, 0, 0, 0);
      pbb = __builtin_amdgcn_mfma_f32_32x32x16_bf16(yj, xj[ks], pbb, 0, 0, 0);
      paa = __builtin_amdgcn_mfma_f32_32x32x16_bf16(yi, xi[ks], paa, 0, 0, 0);
      pba = __builtin_amdgcn_mfma_f32_32x32x16_bf16(yi, xj[ks], pba, 0, 0, 0);
    }
    if (jt < 7) {  // write-late: staging lands after the MFMAs
      *reinterpret_cast<short8*>(&yt[nxt][0][tid * 8]) = tj0;
      *reinterpret_cast<short8*>(&yt[nxt][1][tid * 8]) = ti0;
      *reinterpret_cast<short8*>(&yt[nxt][0][(tid + 256) * 8]) = tj1;
      *reinterpret_cast<short8*>(&yt[nxt][1][(tid + 256) * 8]) = ti1;
    }
#pragma unroll
    for (int r = 0; r < 16; ++r) {
      float eab = EX2(pab[r]);
      float ebb = EX2(pbb[r]);
      float eaa = EX2(paa[r]);
      float eba = EX2(pba[r]);
      if (dt && ((dmask >> r) & 1u)) { ebb = 0.0f; eaa = 0.0f; }  // diag skips
      ra[r] += eab + eaa;
      rb[r] += ebb + eba;
    }
    __syncthreads();  // nxt fully staged; cur free for overwrite next iter
  }
  // LDS reduce (2 lanes x 16 regs share each output row)
#pragma unroll
  for (int r = 0; r < 16; ++r) {
    int im = (imv[r >> 2] >> ((r & 3) * 8)) & 0xFF;
    atomicAdd(&bufa[wid * 32 + im], ra[r]);
    atomicAdd(&bufb[wid * 32 + im], rb[r]);
  }
  __syncthreads();
  if (tid < 128) {
    rowp_a[(size_t)blockIdx.y * NB + blockIdx.x * 128 + tid] = bufa[tid];
    rowp_b[(size_t)blockIdx.y * NB + blockIdx.x * 128 + tid] = bufb[tid];
  }
}

// loss = mean(0.5*(ln sa + ln sb) - diagn)   (e^{+20} scale cancels in ln)
__global__ __launch_bounds__(256) void k_final(
    const float* __restrict__ rowp_a, const float* __restrict__ rowp_b,
    const float* __restrict__ diagn, float* __restrict__ out) {
  int i = blockIdx.x * 256 + threadIdx.x;
  float sa = 0.0f, sb = 0.0f;
#pragma unroll
  for (int y = 0; y < 16; ++y) {
    sa += rowp_a[(size_t)y * NB + i];
    sb += rowp_b[(size_t)y * NB + i];
  }
  float v = 0.5f * (logf(sa) + logf(sb)) - diagn[i];
  v = wave_sum(v);
  __shared__ float sred[4];
  if ((threadIdx.x & 63) == 0) sred[threadIdx.x >> 6] = v;
  __syncthreads();
  if (threadIdx.x == 0)
    atomicAdd(out, (sred[0] + sred[1] + sred[2] + sred[3]) * (1.0f / NB));
}

extern "C" void kernel_launch(void* const* d_in, const int* in_sizes, int n_in,
                              void* d_out, int out_size, void* d_ws, size_t ws_size,
                              hipStream_t stream) {
  const float* emb = (const float*)d_in[0];
  const int* links = (const int*)d_in[1];
  char* ws = (char*)d_ws;
  unsigned short* Zic = (unsigned short*)(ws + 0);       // 1 MB
  unsigned short* Zjc = (unsigned short*)(ws + 1048576); // 1 MB
  float* rowp_a = (float*)(ws + 2097152);                // 16*4096*4 = 256 KB
  float* rowp_b = (float*)(ws + 2359296);                // 256 KB
  float* diagn = (float*)(ws + 2621440);                 // 16 KB
  int* flag = (int*)(ws + 2637824);                      // 4 B
  float* out = (float*)d_out;

  hipLaunchKernelGGL(k_init, dim3(1), dim3(64), 0, stream, links, flag, out);
  hipLaunchKernelGGL(k_normalize, dim3(1024), dim3(256), 0, stream,
                     emb, links, flag, Zic, Zjc, diagn);
  hipLaunchKernelGGL(k_pass, dim3(32, 16), dim3(256), 0, stream,
                     Zic, Zjc, rowp_a, rowp_b);
  hipLaunchKernelGGL(k_final, dim3(16), dim3(256), 0, stream,
                     rowp_a, rowp_b, diagn, out);
}